// Round 2
// baseline (427.046 us; speedup 1.0000x reference)
//
#include <hip/hip_runtime.h>
#include <hip/hip_bf16.h>

// Problem constants
#define NN 16
#define CF 768
#define CC 64
#define HH 56
#define WW 56
#define SS 40
#define PP (SS*SS)          // 1600 positions per image
#define PPAD 1664           // padded to 13*128
#define NPT (NN*PP)         // 25600
#define NPTP (NN*PPAD)      // 26624
#define HWP (HH*WW)         // 3136

typedef __attribute__((ext_vector_type(8))) short short8;
typedef __attribute__((ext_vector_type(4))) float f32x4;

typedef const __attribute__((address_space(1))) void* gas_p;
typedef __attribute__((address_space(3))) void* las_p;

// Shared bilinear helper — EXACT same arithmetic as validated round-1 kernel.
__device__ __forceinline__ void bilin(float gx, float gy,
    int& o00, int& o01, int& o10, int& o11,
    float& w00, float& w01, float& w10, float& w11)
{
    float x = (gx + 1.f) * 0.5f * (float)(WW - 1);
    float y = (gy + 1.f) * 0.5f * (float)(HH - 1);
    x = fminf(fmaxf(x, 0.f), (float)(WW - 1));
    y = fminf(fmaxf(y, 0.f), (float)(HH - 1));
    float xf = floorf(x), yf = floorf(y);
    int x0 = (int)xf, y0 = (int)yf;
    int x1 = min(x0 + 1, WW - 1), y1 = min(y0 + 1, HH - 1);
    float wx = x - xf, wy = y - yf;
    w00 = (1.f-wx)*(1.f-wy); w01 = wx*(1.f-wy); w10 = (1.f-wx)*wy; w11 = wx*wy;
    o00 = y0*WW + x0; o01 = y0*WW + x1; o10 = y1*WW + x0; o11 = y1*WW + x1;
}

// ---------------------------------------------------------------------------
// Kernel 1: sampling — VERBATIM validated kernel.
// ---------------------------------------------------------------------------
__global__ __launch_bounds__(256) void k_sample(
    const float* __restrict__ f0, const float* __restrict__ f1,
    const float* __restrict__ c0in, const float* __restrict__ c1in,
    const float* __restrict__ g0, const float* __restrict__ g1,
    float* __restrict__ nrmF, float* __restrict__ nrmC,
    short* __restrict__ OF0, short* __restrict__ OF1,
    short* __restrict__ OC0, short* __restrict__ OC1)
{
    // decode quarter-interleaved flat index
    const int flat = blockIdx.x;                       // [0, 3328)
    const int q    = (flat >> 3) & 3;                  // quarter
    const int u    = ((flat >> 5) << 3) | (flat & 7);  // [0, 832)
    const int set  = u / 416;                          // 26*16 = 416
    const int rem  = u % 416;
    const int n    = rem / 26;
    const int v    = rem % 26;                         // 0..23 feats, 24..25 code
    const bool isF = v < 24;
    const int ks   = isF ? v : v - 24;
    const int g    = ks * 4 + q;                       // 8-channel group index

    const float* src0; float* nrm; short* out; int NKS;
    if (isF) {
        src0 = (set ? f1 : f0) + ((size_t)n * CF + g * 8) * HWP;
        nrm  = nrmF + (size_t)set * NPTP;
        out  = set ? OF1 : OF0;
        NKS  = 24;
    } else {
        src0 = (set ? c1in : c0in) + ((size_t)n * CC + g * 8) * HWP;
        nrm  = nrmC + (size_t)set * NPTP;
        out  = set ? OC1 : OC0;
        NKS  = 2;
    }
    const float* gr = set ? g1 : g0;
    const int t = threadIdx.x;
    __shared__ float plane[4 * HWP];   // 50 KB
    float keep[7][4];

    // [n][ks][p][32] layout: base of this block's quarter
    const size_t obase = ((size_t)(n * NKS + ks)) * PPAD * 32 + q * 8;

    #pragma unroll
    for (int h = 0; h < 2; h++) {
        if (h) __syncthreads();                 // phase-0 compute done
        const float4* s4 = (const float4*)(src0 + (size_t)h * 4 * HWP);
        #pragma unroll
        for (int i = 0; i < 13; i++) {
            int j = t + i * 256;
            if (j < HWP) ((float4*)plane)[j] = s4[j];
        }
        __syncthreads();

        #pragma unroll
        for (int i = 0; i < 7; i++) {
            int p = t + i * 256;
            if (p >= PPAD) continue;
            if (p < PP) {
                int pg = n * PP + p;
                float2 gg = *(const float2*)&gr[2 * pg];
                int o00, o01, o10, o11; float w00, w01, w10, w11;
                bilin(gg.x*2.f - 1.f, gg.y*2.f - 1.f, o00, o01, o10, o11, w00, w01, w10, w11);
                float v4[4];
                #pragma unroll
                for (int k = 0; k < 4; k++) {
                    const float* pl = plane + k * HWP;
                    v4[k] = w00*pl[o00] + w01*pl[o01] + w10*pl[o10] + w11*pl[o11];
                }
                if (h == 0) {
                    #pragma unroll
                    for (int k = 0; k < 4; k++) keep[i][k] = v4[k];
                } else {
                    float ss = 0.f;
                    short ov[8] __attribute__((aligned(16)));
                    #pragma unroll
                    for (int k = 0; k < 4; k++) {
                        ss += keep[i][k]*keep[i][k] + v4[k]*v4[k];
                        __hip_bfloat16 b0 = __float2bfloat16(keep[i][k]);
                        __hip_bfloat16 b1 = __float2bfloat16(v4[k]);
                        ov[k]     = *(short*)&b0;
                        ov[4 + k] = *(short*)&b1;
                    }
                    *(short8*)&out[obase + (size_t)p * 32] = *(const short8*)ov;
                    atomicAdd(&nrm[n * PPAD + p], ss);
                }
            } else if (h == 1) {
                short8 z = {0,0,0,0,0,0,0,0};
                *(short8*)&out[obase + (size_t)p * 32] = z;
            }
        }
    }
}

// ---------------------------------------------------------------------------
// Kernel 2: nrm -> scale (validated). Pad rows -> scale 0.
// ---------------------------------------------------------------------------
__global__ __launch_bounds__(256) void k_nrm(
    const float* __restrict__ nrmF, const float* __restrict__ nrmC,
    float* __restrict__ sclF, float* __restrict__ sclC)
{
    const int i = blockIdx.x * 256 + threadIdx.x;    // [0, 2*NPTP)
    if (i >= 2 * NPTP) return;
    const float* nrm = blockIdx.y ? nrmC : nrmF;
    float*       scl = blockIdx.y ? sclC : sclF;
    const int p = i % PPAD;
    float s = (p < PP) ? 1.f / fmaxf(sqrtf(nrm[i]), 1e-10f) : 0.f;
    scl[i] = s;
}

// ---------------------------------------------------------------------------
// Kernel 3: fused dual correlation GEMM — round 17: 256x256 tile, 8 waves
// (512 thr), BK=64, double-buffered 8-phase schedule (m201 template).
// Per phase: {4-8 ds_read_b128 || 2 global_load_lds || [vmcnt(4)] || barrier
// || 16 MFMA (setprio-wrapped) || barrier}. vmcnt(4) only at phases 2&4 of
// each K-tile (counted, never 0 in loop). Quadrants Q(m-half, kk): B-frags
// live 2 phases. fd = 12 K-tiles; iteration 12's prefetch target is the cd
// K-tile (K=64) -> buf0; epilogue computes cd per-m (validated round-16
// logic) with transient 16-reg accumulator. XOR bank swizzle + clamped pad
// rows + XCD-chunked swizzle all verbatim from validated kernels.
// ---------------------------------------------------------------------------
__global__ __launch_bounds__(512, 2) void k_corr(
    const short* __restrict__ A, const short* __restrict__ B,
    const short* __restrict__ C, const short* __restrict__ D,
    const float* __restrict__ sF, const float* __restrict__ sC,
    float* __restrict__ rowfd, float* __restrict__ rowrc, float* __restrict__ t1out)
{
    // XCD-chunked swizzle: 784 blocks = 8 XCDs x 98 (bijective)
    const int flat = blockIdx.x;
    const int v   = (flat & 7) * 98 + (flat >> 3);
    const int n   = v / 49;                 // 7 M-tiles x 7 N-tiles per n
    const int rr  = v - n * 49;
    const int bp1 = (rr / 7) * 256;         // M tile base (rows clamp at 1663)
    const int bp2 = (rr % 7) * 256;         // N tile base (cols clamp at 1663)

    __shared__ short As[2][2][8192];   // [buf][kk][256 rows x 32] = 64 KB
    __shared__ short Bs[2][2][8192];   // 64 KB

    const int t    = threadIdx.x;
    const int wv   = t >> 6, lane = t & 63;
    const int wm   = wv >> 2, wn = wv & 3;           // 2 M-halves x 4 N-quads
    const int frow = lane & 15, fcg = lane >> 4;     // fragment row / k-chunk
    const int fslot = fcg ^ ((frow >> 1) & 3);       // bank-swizzled slot

    // staging geometry: per sub-slab (256 rows x 32 shorts = 16KB),
    // 512 threads x 2 chunks of 8 shorts. chunk g = (wv*2+j)*64 + lane.
    int aoff[2], boff[2], alds[2];
    #pragma unroll
    for (int j = 0; j < 2; j++) {
        int g   = (wv * 2 + j) * 64 + lane;          // [0,1024)
        int row = g >> 2;                            // [0,256)
        int cg  = (g & 3) ^ ((row >> 1) & 3);        // write-side XOR swizzle
        aoff[j] = min(bp1 + row, PPAD - 1) * 32 + cg * 8;  // clamp: pad rows zero
        boff[j] = min(bp2 + row, PPAD - 1) * 32 + cg * 8;
        alds[j] = (wv * 2 + j) * 512;                // wave-uniform LDS base (shorts)
    }

    const size_t kstep = (size_t)PPAD * 32;          // shorts per BK=32 slab
    const short* fdA = A + (size_t)n * 24 * kstep;
    const short* fdB = B + (size_t)n * 24 * kstep;
    const short* cdC = C + (size_t)n * 2 * kstep;
    const short* cdD = D + (size_t)n * 2 * kstep;

    auto* As3 = (__attribute__((address_space(3))) short*)&As[0][0][0];
    auto* Bs3 = (__attribute__((address_space(3))) short*)&Bs[0][0][0];

#define STAGEA(SRC, BUF, KK)                                                        \
    do {                                                                            \
        _Pragma("unroll")                                                           \
        for (int j_ = 0; j_ < 2; j_++)                                              \
            __builtin_amdgcn_global_load_lds((gas_p)((SRC) + aoff[j_]),             \
                (las_p)(As3 + ((BUF) * 2 + (KK)) * 8192 + alds[j_]), 16, 0, 0);     \
    } while (0)
#define STAGEB(SRC, BUF, KK)                                                        \
    do {                                                                            \
        _Pragma("unroll")                                                           \
        for (int j_ = 0; j_ < 2; j_++)                                              \
            __builtin_amdgcn_global_load_lds((gas_p)((SRC) + boff[j_]),             \
                (las_p)(Bs3 + ((BUF) * 2 + (KK)) * 8192 + alds[j_]), 16, 0, 0);     \
    } while (0)

#define LDA(BUF, KK, M) (*(const short8*)&As[BUF][KK][(wm*128 + (M)*16 + frow)*32 + fslot*8])
#define LDB(BUF, KK, Q) (*(const short8*)&Bs[BUF][KK][(wn*64  + (Q)*16 + frow)*32 + fslot*8])

#define BARX do { __builtin_amdgcn_sched_barrier(0);                                \
                  __builtin_amdgcn_s_barrier(); } while (0)
#define VW4  asm volatile("s_waitcnt vmcnt(4)" ::: "memory")
#define NOWAIT ((void)0)

// One phase: ds-reads + stage (first segment), optional wait, barrier,
// MFMA quadrant (second segment), barrier. All indices compile-time.
#define PHASE(CUR, KK, MB, LOADB, STAGE_STMT, WAIT_STMT)                            \
    do {                                                                            \
        short8 av_[4];                                                              \
        _Pragma("unroll")                                                           \
        for (int m_ = 0; m_ < 4; m_++) av_[m_] = LDA(CUR, KK, (MB) + m_);           \
        if (LOADB) {                                                                \
            _Pragma("unroll")                                                       \
            for (int q_ = 0; q_ < 4; q_++) bk[q_] = LDB(CUR, KK, q_);               \
        }                                                                           \
        STAGE_STMT;                                                                 \
        WAIT_STMT;                                                                  \
        BARX;                                                                       \
        __builtin_amdgcn_s_setprio(1);                                              \
        _Pragma("unroll")                                                           \
        for (int m_ = 0; m_ < 4; m_++)                                              \
            _Pragma("unroll")                                                       \
            for (int q_ = 0; q_ < 4; q_++)                                          \
                accfd[(MB) + m_][q_] = __builtin_amdgcn_mfma_f32_16x16x32_bf16(     \
                    av_[m_], bk[q_], accfd[(MB) + m_][q_], 0, 0, 0);                \
        __builtin_amdgcn_s_setprio(0);                                              \
        BARX;                                                                       \
    } while (0)

    f32x4 accfd[8][4];
    #pragma unroll
    for (int m = 0; m < 8; m++)
        #pragma unroll
        for (int q = 0; q < 4; q++)
            #pragma unroll
            for (int r = 0; r < 4; r++) accfd[m][q][r] = 0.f;

    // ---- prologue: stage K-tile 0 (groups A0,B0,A1,B1), wait first half ----
    STAGEA(fdA, 0, 0);
    STAGEB(fdB, 0, 0);
    STAGEA(fdA + kstep, 0, 1);
    STAGEB(fdB + kstep, 0, 1);
    VW4;
    BARX;

    // ---- main loop: 12 fd K-tiles, 2 per iteration (buf0 then buf1) ----
    for (int kti = 0; kti < 6; kti++) {
        const short* pA1 = fdA + (size_t)(4 * kti + 2) * kstep;   // K-tile 2kti+1
        const short* pB1 = fdB + (size_t)(4 * kti + 2) * kstep;
        const short* pA2 = (kti < 5) ? fdA + (size_t)(4 * kti + 4) * kstep : cdC;
        const short* pB2 = (kti < 5) ? fdB + (size_t)(4 * kti + 4) * kstep : cdD;
        short8 bk[4];
        // K-tile 2kti (buf0), staging K-tile 2kti+1 -> buf1
        PHASE(0, 0, 0, 1, STAGEA(pA1, 1, 0),         NOWAIT);
        PHASE(0, 0, 4, 0, STAGEB(pB1, 1, 0),         VW4);
        PHASE(0, 1, 0, 1, STAGEA(pA1 + kstep, 1, 1), NOWAIT);
        PHASE(0, 1, 4, 0, STAGEB(pB1 + kstep, 1, 1), VW4);
        // K-tile 2kti+1 (buf1), staging next -> buf0 (kti==5: cd tile)
        PHASE(1, 0, 0, 1, STAGEA(pA2, 0, 0),         NOWAIT);
        PHASE(1, 0, 4, 0, STAGEB(pB2, 0, 0),         VW4);
        PHASE(1, 1, 0, 1, STAGEA(pA2 + kstep, 0, 1), NOWAIT);
        PHASE(1, 1, 4, 0, STAGEB(pB2 + kstep, 0, 1), VW4);
    }

    // ---- drain: cd tile fully landed in buf0 ----
    asm volatile("s_waitcnt vmcnt(0)" ::: "memory");
    BARX;
#undef PHASE
#undef STAGEA
#undef STAGEB
#undef VW4
#undef NOWAIT

    // ---- epilogue: cd GEMM (K=64 from buf0) + scales + t1 + row sums ----
    // (validated round-16 logic; col scale index now clamped for BN=256 overhang)
    short8 bc0[4], bc1[4];
    #pragma unroll
    for (int q = 0; q < 4; q++) {
        bc0[q] = LDB(0, 0, q);
        bc1[q] = LDB(0, 1, q);
    }
    float sfc_[4], scc_[4];
    #pragma unroll
    for (int q = 0; q < 4; q++) {
        int c = min(bp2 + wn*64 + q*16 + frow, PPAD - 1);   // pad cols -> scale 0
        size_t colp = (size_t)NPTP + (size_t)n * PPAD + c;
        scc_[q] = sC[colp];
        sfc_[q] = sF[colp];
    }

    // C/D layout: col = lane&15, row = (lane>>4)*4 + reg
    float t1 = 0.f;
    #pragma unroll
    for (int m = 0; m < 8; m++) {
        f32x4 a2[4];
        #pragma unroll
        for (int q = 0; q < 4; q++)
            #pragma unroll
            for (int r = 0; r < 4; r++) a2[q][r] = 0.f;
        short8 ac0 = LDA(0, 0, m);
        short8 ac1 = LDA(0, 1, m);
        #pragma unroll
        for (int q = 0; q < 4; q++) {
            a2[q] = __builtin_amdgcn_mfma_f32_16x16x32_bf16(ac0, bc0[q], a2[q], 0, 0, 0);
            a2[q] = __builtin_amdgcn_mfma_f32_16x16x32_bf16(ac1, bc1[q], a2[q], 0, 0, 0);
        }
        #pragma unroll
        for (int r = 0; r < 4; r++) {
            int row  = bp1 + wm*128 + m*16 + fcg*4 + r;
            int rowc = min(row, PPAD - 1);            // clamped rows have acc==0
            float scr = sC[n * PPAD + rowc];
            float sfr = sF[n * PPAD + rowc];
            float sf = 0.f, sr = 0.f;
            #pragma unroll
            for (int q = 0; q < 4; q++) {
                float fdv = accfd[m][q][r] * sfr * sfc_[q];
                float rcv = fmaxf(a2[q][r], 0.f) * scr * scc_[q];
                t1 += rcv * fdv;
                sf += fdv;
                sr += rcv;
            }
            #pragma unroll
            for (int d = 1; d < 16; d <<= 1) {
                sf += __shfl_xor(sf, d, 64);
                sr += __shfl_xor(sr, d, 64);
            }
            if ((lane & 15) == 0 && row < PPAD) {
                atomicAdd(&rowfd[n * PPAD + row], sf);
                atomicAdd(&rowrc[n * PPAD + row], sr);
            }
        }
    }
#undef LDA
#undef LDB
#undef BARX
    #pragma unroll
    for (int d = 1; d < 64; d <<= 1) t1 += __shfl_xor(t1, d, 64);
    if (lane == 0) atomicAdd(t1out, t1);   // 8 atomics/block, trivial contention
}

// ---------------------------------------------------------------------------
// Kernel 4: finalize. loss = -(T1 - cross/PP + (Sfd/M)*Src)/M
// ---------------------------------------------------------------------------
__global__ __launch_bounds__(256) void k_final(
    const float* __restrict__ rowfd, const float* __restrict__ rowrc,
    const float* __restrict__ t1p, float* __restrict__ out)
{
    const int t = threadIdx.x;
    double cr = 0.0, sf = 0.0, sr = 0.0;
    for (int i = t; i < NN * PPAD; i += 256) {
        double a = rowfd[i], b = rowrc[i];
        cr += a * b; sf += a; sr += b;
    }
    __shared__ double sh[256];
    sh[t] = cr; __syncthreads();
    for (int s = 128; s > 0; s >>= 1) { if (t < s) sh[t] += sh[t + s]; __syncthreads(); }
    cr = sh[0]; __syncthreads();
    sh[t] = sf; __syncthreads();
    for (int s = 128; s > 0; s >>= 1) { if (t < s) sh[t] += sh[t + s]; __syncthreads(); }
    sf = sh[0]; __syncthreads();
    sh[t] = sr; __syncthreads();
    for (int s = 128; s > 0; s >>= 1) { if (t < s) sh[t] += sh[t + s]; __syncthreads(); }
    sr = sh[0];
    if (t == 0) {
        double M = (double)NN * (double)PP * (double)PP;
        double t1 = (double)t1p[0];
        double bracket = t1 - cr / (double)PP + (sf / M) * sr;
        out[0] = (float)(-bracket / M);
    }
}

// ---------------------------------------------------------------------------
extern "C" void kernel_launch(void* const* d_in, const int* in_sizes, int n_in,
                              void* d_out, int out_size, void* d_ws, size_t ws_size,
                              hipStream_t stream)
{
    const float* orig_feats     = (const float*)d_in[0];
    const float* orig_feats_pos = (const float*)d_in[1];
    const float* orig_code      = (const float*)d_in[2];
    const float* orig_code_pos  = (const float*)d_in[3];
    const float* coords1        = (const float*)d_in[4];
    const float* coords2        = (const float*)d_in[5];

    // ---- workspace layout (total 89,669,888 B) ----
    char* ws = (char*)d_ws;
    float* t1    = (float*)(ws + 0);                      //      256 B
    float* rowfd = (float*)(ws + 256);                    //  106,496 B (NN*PPAD)
    float* rowrc = (float*)(ws + 106752);                 //  106,496 B
    float* nrmF  = (float*)(ws + 213248);                 //  212,992 B (2*NPTP)
    float* nrmC  = (float*)(ws + 426240);                 //  212,992 B
    const size_t zeroBytes = 639232;                      // t1+rowsums+nrms
    float* sclF  = (float*)(ws + 639232);                 //  212,992 B
    float* sclC  = (float*)(ws + 852224);                 //  212,992 B
    short* OF0 = (short*)(ws + 1065216);                  // [16][24][1664][32] bf16
    short* OF1 = (short*)(ws + 1065216 + 40894464ull);
    short* OC0 = (short*)(ws + 1065216 + 2*40894464ull);  // [16][2][1664][32] bf16
    short* OC1 = (short*)(ws + 1065216 + 2*40894464ull + 3407872ull);

    (void)hipMemsetAsync(d_ws, 0, zeroBytes, stream);   // t1/rowsums/nrms

    k_sample<<<dim3(3328), 256, 0, stream>>>(
        orig_feats, orig_feats_pos, orig_code, orig_code_pos,
        coords1, coords2, nrmF, nrmC, OF0, OF1, OC0, OC1);

    k_nrm<<<dim3((2*NPTP + 255)/256, 2), 256, 0, stream>>>(
        nrmF, nrmC, sclF, sclC);

    k_corr<<<dim3(784), 512, 0, stream>>>(
        OF0, OF1, OC0, OC1, sclF, sclC, rowfd, rowrc, t1);

    k_final<<<1, 256, 0, stream>>>(rowfd, rowrc, t1, (float*)d_out);
}

// Round 3
// 342.638 us; speedup vs baseline: 1.2463x; 1.2463x over previous
//
#include <hip/hip_runtime.h>
#include <hip/hip_bf16.h>

// Problem constants
#define NN 16
#define CF 768
#define CC 64
#define HH 56
#define WW 56
#define SS 40
#define PP (SS*SS)          // 1600 positions per image
#define PPAD 1664           // padded to 13*128
#define NPT (NN*PP)         // 25600
#define NPTP (NN*PPAD)      // 26624
#define HWP (HH*WW)         // 3136

typedef __attribute__((ext_vector_type(8))) short short8;
typedef __attribute__((ext_vector_type(4))) float f32x4;

typedef const __attribute__((address_space(1))) void* gas_p;
typedef __attribute__((address_space(3))) void* las_p;

// Shared bilinear helper — EXACT same arithmetic as validated round-1 kernel.
__device__ __forceinline__ void bilin(float gx, float gy,
    int& o00, int& o01, int& o10, int& o11,
    float& w00, float& w01, float& w10, float& w11)
{
    float x = (gx + 1.f) * 0.5f * (float)(WW - 1);
    float y = (gy + 1.f) * 0.5f * (float)(HH - 1);
    x = fminf(fmaxf(x, 0.f), (float)(WW - 1));
    y = fminf(fmaxf(y, 0.f), (float)(HH - 1));
    float xf = floorf(x), yf = floorf(y);
    int x0 = (int)xf, y0 = (int)yf;
    int x1 = min(x0 + 1, WW - 1), y1 = min(y0 + 1, HH - 1);
    float wx = x - xf, wy = y - yf;
    w00 = (1.f-wx)*(1.f-wy); w01 = wx*(1.f-wy); w10 = (1.f-wx)*wy; w11 = wx*wy;
    o00 = y0*WW + x0; o01 = y0*WW + x1; o10 = y1*WW + x0; o11 = y1*WW + x1;
}

// ---------------------------------------------------------------------------
// Kernel 1: sampling — VERBATIM validated kernel.
// ---------------------------------------------------------------------------
__global__ __launch_bounds__(256) void k_sample(
    const float* __restrict__ f0, const float* __restrict__ f1,
    const float* __restrict__ c0in, const float* __restrict__ c1in,
    const float* __restrict__ g0, const float* __restrict__ g1,
    float* __restrict__ nrmF, float* __restrict__ nrmC,
    short* __restrict__ OF0, short* __restrict__ OF1,
    short* __restrict__ OC0, short* __restrict__ OC1)
{
    // decode quarter-interleaved flat index
    const int flat = blockIdx.x;                       // [0, 3328)
    const int q    = (flat >> 3) & 3;                  // quarter
    const int u    = ((flat >> 5) << 3) | (flat & 7);  // [0, 832)
    const int set  = u / 416;                          // 26*16 = 416
    const int rem  = u % 416;
    const int n    = rem / 26;
    const int v    = rem % 26;                         // 0..23 feats, 24..25 code
    const bool isF = v < 24;
    const int ks   = isF ? v : v - 24;
    const int g    = ks * 4 + q;                       // 8-channel group index

    const float* src0; float* nrm; short* out; int NKS;
    if (isF) {
        src0 = (set ? f1 : f0) + ((size_t)n * CF + g * 8) * HWP;
        nrm  = nrmF + (size_t)set * NPTP;
        out  = set ? OF1 : OF0;
        NKS  = 24;
    } else {
        src0 = (set ? c1in : c0in) + ((size_t)n * CC + g * 8) * HWP;
        nrm  = nrmC + (size_t)set * NPTP;
        out  = set ? OC1 : OC0;
        NKS  = 2;
    }
    const float* gr = set ? g1 : g0;
    const int t = threadIdx.x;
    __shared__ float plane[4 * HWP];   // 50 KB
    float keep[7][4];

    // [n][ks][p][32] layout: base of this block's quarter
    const size_t obase = ((size_t)(n * NKS + ks)) * PPAD * 32 + q * 8;

    #pragma unroll
    for (int h = 0; h < 2; h++) {
        if (h) __syncthreads();                 // phase-0 compute done
        const float4* s4 = (const float4*)(src0 + (size_t)h * 4 * HWP);
        #pragma unroll
        for (int i = 0; i < 13; i++) {
            int j = t + i * 256;
            if (j < HWP) ((float4*)plane)[j] = s4[j];
        }
        __syncthreads();

        #pragma unroll
        for (int i = 0; i < 7; i++) {
            int p = t + i * 256;
            if (p >= PPAD) continue;
            if (p < PP) {
                int pg = n * PP + p;
                float2 gg = *(const float2*)&gr[2 * pg];
                int o00, o01, o10, o11; float w00, w01, w10, w11;
                bilin(gg.x*2.f - 1.f, gg.y*2.f - 1.f, o00, o01, o10, o11, w00, w01, w10, w11);
                float v4[4];
                #pragma unroll
                for (int k = 0; k < 4; k++) {
                    const float* pl = plane + k * HWP;
                    v4[k] = w00*pl[o00] + w01*pl[o01] + w10*pl[o10] + w11*pl[o11];
                }
                if (h == 0) {
                    #pragma unroll
                    for (int k = 0; k < 4; k++) keep[i][k] = v4[k];
                } else {
                    float ss = 0.f;
                    short ov[8] __attribute__((aligned(16)));
                    #pragma unroll
                    for (int k = 0; k < 4; k++) {
                        ss += keep[i][k]*keep[i][k] + v4[k]*v4[k];
                        __hip_bfloat16 b0 = __float2bfloat16(keep[i][k]);
                        __hip_bfloat16 b1 = __float2bfloat16(v4[k]);
                        ov[k]     = *(short*)&b0;
                        ov[4 + k] = *(short*)&b1;
                    }
                    *(short8*)&out[obase + (size_t)p * 32] = *(const short8*)ov;
                    atomicAdd(&nrm[n * PPAD + p], ss);
                }
            } else if (h == 1) {
                short8 z = {0,0,0,0,0,0,0,0};
                *(short8*)&out[obase + (size_t)p * 32] = z;
            }
        }
    }
}

// ---------------------------------------------------------------------------
// Kernel 2: nrm -> scale (validated). Pad rows -> scale 0.
// ---------------------------------------------------------------------------
__global__ __launch_bounds__(256) void k_nrm(
    const float* __restrict__ nrmF, const float* __restrict__ nrmC,
    float* __restrict__ sclF, float* __restrict__ sclC)
{
    const int i = blockIdx.x * 256 + threadIdx.x;    // [0, 2*NPTP)
    if (i >= 2 * NPTP) return;
    const float* nrm = blockIdx.y ? nrmC : nrmF;
    float*       scl = blockIdx.y ? sclC : sclF;
    const int p = i % PPAD;
    float s = (p < PP) ? 1.f / fmaxf(sqrtf(nrm[i]), 1e-10f) : 0.f;
    scl[i] = s;
}

// ---------------------------------------------------------------------------
// Kernel 3: fused dual correlation GEMM — round 18: the VALIDATED round-15
// 3-buffer counted-vmcnt pipeline (1 barrier/step, stage 2-ahead), widened
// to 8 waves / 256x128 tile, with cd moved to the epilogue (validated in
// rounds 1-2) to free the 32-VGPR pcd array. Per-wave tile stays 64x64
// (acc = 64 AGPR). launch_bounds(512,4) caps regs at 128 -> 4 waves/SIMD
// (16 waves/CU, 2 blocks/CU by LDS 72KB). Occupancy is the lever: the
// baseline is latency-bound at 12 waves/CU (regs 148/wave).
// ---------------------------------------------------------------------------
__global__ __launch_bounds__(512, 4) void k_corr(
    const short* __restrict__ A, const short* __restrict__ B,
    const short* __restrict__ C, const short* __restrict__ D,
    const float* __restrict__ sF, const float* __restrict__ sC,
    float* __restrict__ rowfd, float* __restrict__ rowrc, float* __restrict__ t1out)
{
    // XCD-chunked swizzle: 1456 blocks = 8 XCDs x 182 (bijective)
    const int flat = blockIdx.x;
    const int v   = (flat & 7) * 182 + (flat >> 3);
    const int n   = v / 91;                 // 7 M-tiles x 13 N-tiles per n
    const int rr  = v - n * 91;
    const int bp1 = (rr / 13) * 256;        // M tile base (rows clamp at 1663)
    const int bp2 = (rr % 13) * 128;        // N tile base (exact)

    __shared__ short As[3][8192];   // 3 x 16KB (256 rows x 32 k)
    __shared__ short Bs[3][4096];   // 3 x 8KB  (128 rows x 32 k)
    __shared__ float t1s[8];

    const int t    = threadIdx.x;
    const int wv   = t >> 6, lane = t & 63;
    const int wm   = wv >> 1, wn = wv & 1;           // 4 M-quads x 2 N-halves
    const int frow = lane & 15, fcg = lane >> 4;     // fragment row / k-chunk
    const int fslot = fcg ^ ((frow >> 1) & 3);       // bank-swizzled slot

    // staging geometry: A = 1024 chunks of 16B (2/thread), B = 512 (1/thread)
    int aoff[2];
    #pragma unroll
    for (int j = 0; j < 2; j++) {
        int g   = wv * 64 + lane + j * 512;          // [0,1024)
        int row = g >> 2;                            // [0,256)
        int cg  = (g & 3) ^ ((row >> 1) & 3);        // write-side XOR swizzle
        aoff[j] = min(bp1 + row, PPAD - 1) * 32 + cg * 8;  // clamp: pad rows zero
    }
    int boff;
    {
        int g   = wv * 64 + lane;                    // [0,512)
        int row = g >> 2;                            // [0,128)
        int cg  = (g & 3) ^ ((row >> 1) & 3);
        boff    = (bp2 + row) * 32 + cg * 8;
    }
    const int ldsW = wv * 512;                       // wave-uniform LDS base (shorts)

    const size_t kstep = (size_t)PPAD * 32;          // shorts per BK=32 step
    const short* fdA = A + (size_t)n * 24 * kstep;
    const short* fdB = B + (size_t)n * 24 * kstep;
    const short* cdC = C + (size_t)n * 2 * kstep;
    const short* cdD = D + (size_t)n * 2 * kstep;

    auto* As3 = (__attribute__((address_space(3))) short*)&As[0][0];
    auto* Bs3 = (__attribute__((address_space(3))) short*)&Bs[0][0];

#define STAGE(PA, PB, OFF, BUF)                                                     \
    do {                                                                            \
        const size_t off_ = (OFF);                                                  \
        __builtin_amdgcn_global_load_lds((gas_p)((PA) + aoff[0] + off_),            \
            (las_p)(As3 + (BUF) * 8192 + ldsW), 16, 0, 0);                          \
        __builtin_amdgcn_global_load_lds((gas_p)((PA) + aoff[1] + off_),            \
            (las_p)(As3 + (BUF) * 8192 + ldsW + 4096), 16, 0, 0);                   \
        __builtin_amdgcn_global_load_lds((gas_p)((PB) + boff + off_),               \
            (las_p)(Bs3 + (BUF) * 4096 + ldsW), 16, 0, 0);                          \
    } while (0)

#define COMPUTE(BUF, ACC)                                                           \
    do {                                                                            \
        short8 bf[4];                                                               \
        _Pragma("unroll")                                                           \
        for (int q = 0; q < 4; q++)                                                 \
            bf[q] = *(const short8*)&Bs[BUF][(wn*64 + q*16 + frow)*32 + fslot*8];   \
        _Pragma("unroll")                                                           \
        for (int m = 0; m < 4; m++) {                                               \
            short8 af = *(const short8*)&As[BUF][(wm*64 + m*16 + frow)*32 + fslot*8]; \
            _Pragma("unroll")                                                       \
            for (int q = 0; q < 4; q++)                                             \
                ACC[m][q] = __builtin_amdgcn_mfma_f32_16x16x32_bf16(af, bf[q], ACC[m][q], 0, 0, 0); \
        }                                                                           \
    } while (0)

#define WAITV3  do { asm volatile("s_waitcnt vmcnt(3)" ::: "memory");               \
                     __builtin_amdgcn_sched_barrier(0);                             \
                     __builtin_amdgcn_s_barrier(); } while (0)
#define WAITV0  do { asm volatile("s_waitcnt vmcnt(0)" ::: "memory");               \
                     __builtin_amdgcn_sched_barrier(0);                             \
                     __builtin_amdgcn_s_barrier(); } while (0)

    // ---- fd main loop: 24 BK=32 steps, step s -> buf s%3 ----
    f32x4 accfd[4][4];
    #pragma unroll
    for (int m = 0; m < 4; m++)
        #pragma unroll
        for (int q = 0; q < 4; q++)
            #pragma unroll
            for (int r = 0; r < 4; r++) accfd[m][q][r] = 0.f;

    STAGE(fdA, fdB, 0, 0);
    STAGE(fdA, fdB, kstep, 1);

    for (int kp = 0; kp < 8; kp++) {
        const size_t tb = (size_t)(3 * kp) * kstep;
        // slot 0: compute step 3kp (buf0), stage 3kp+2 -> buf2
        WAITV3;
        STAGE(fdA, fdB, tb + 2 * kstep, 2);
        COMPUTE(0, accfd);
        // slot 1: compute step 3kp+1 (buf1), stage 3kp+3 -> buf0
        WAITV3;
        if (kp < 7) STAGE(fdA, fdB, tb + 3 * kstep, 0);
        COMPUTE(1, accfd);
        // slot 2: compute step 3kp+2 (buf2), stage 3kp+4 -> buf1
        if (kp < 7) {
            WAITV3;
            STAGE(fdA, fdB, tb + 4 * kstep, 1);
        } else {
            WAITV0;
        }
        COMPUTE(2, accfd);
    }

    // ---- cd (K=64) staged into freed buffers, computed in epilogue ----
    // safe: all waves passed the final slot barrier; buf0/buf1 reads done.
    __syncthreads();
    STAGE(cdC, cdD, 0, 0);
    STAGE(cdC, cdD, kstep, 1);
    asm volatile("s_waitcnt vmcnt(0)" ::: "memory");
    __builtin_amdgcn_sched_barrier(0);
    __builtin_amdgcn_s_barrier();
#undef STAGE
#undef WAITV3
#undef WAITV0

    // ---- epilogue: cd GEMM (K=64 from buf0/1) + scales + t1 + row sums ----
    float sfc_[4], scc_[4];
    #pragma unroll
    for (int q = 0; q < 4; q++) {
        size_t colp = (size_t)NPTP + (size_t)n * PPAD + bp2 + wn*64 + q*16 + frow;
        scc_[q] = sC[colp];
        sfc_[q] = sF[colp];
    }

    // C/D layout: col = lane&15, row = (lane>>4)*4 + reg
    float t1 = 0.f;
    #pragma unroll
    for (int m = 0; m < 4; m++) {
        f32x4 a2[4];
        #pragma unroll
        for (int q = 0; q < 4; q++)
            #pragma unroll
            for (int r = 0; r < 4; r++) a2[q][r] = 0.f;
        short8 ac0 = *(const short8*)&As[0][(wm*64 + m*16 + frow)*32 + fslot*8];
        short8 ac1 = *(const short8*)&As[1][(wm*64 + m*16 + frow)*32 + fslot*8];
        #pragma unroll
        for (int q = 0; q < 4; q++) {
            short8 bc0 = *(const short8*)&Bs[0][(wn*64 + q*16 + frow)*32 + fslot*8];
            short8 bc1 = *(const short8*)&Bs[1][(wn*64 + q*16 + frow)*32 + fslot*8];
            a2[q] = __builtin_amdgcn_mfma_f32_16x16x32_bf16(ac0, bc0, a2[q], 0, 0, 0);
            a2[q] = __builtin_amdgcn_mfma_f32_16x16x32_bf16(ac1, bc1, a2[q], 0, 0, 0);
        }
        #pragma unroll
        for (int r = 0; r < 4; r++) {
            int row  = bp1 + wm*64 + m*16 + fcg*4 + r;
            int rowc = min(row, PPAD - 1);            // clamped rows have acc==0
            float scr = sC[n * PPAD + rowc];
            float sfr = sF[n * PPAD + rowc];
            float sf = 0.f, sr = 0.f;
            #pragma unroll
            for (int q = 0; q < 4; q++) {
                float fdv = accfd[m][q][r] * sfr * sfc_[q];
                float rcv = fmaxf(a2[q][r], 0.f) * scr * scc_[q];
                t1 += rcv * fdv;
                sf += fdv;
                sr += rcv;
            }
            #pragma unroll
            for (int d = 1; d < 16; d <<= 1) {
                sf += __shfl_xor(sf, d, 64);
                sr += __shfl_xor(sr, d, 64);
            }
            if ((lane & 15) == 0 && row < PPAD) {
                atomicAdd(&rowfd[n * PPAD + row], sf);
                atomicAdd(&rowrc[n * PPAD + row], sr);
            }
        }
    }
#undef COMPUTE
    #pragma unroll
    for (int d = 1; d < 64; d <<= 1) t1 += __shfl_xor(t1, d, 64);
    if (lane == 0) t1s[wv] = t1;
    __syncthreads();
    if (t == 0) {
        float s = 0.f;
        #pragma unroll
        for (int w = 0; w < 8; w++) s += t1s[w];
        atomicAdd(t1out, s);
    }
}

// ---------------------------------------------------------------------------
// Kernel 4: finalize. loss = -(T1 - cross/PP + (Sfd/M)*Src)/M
// ---------------------------------------------------------------------------
__global__ __launch_bounds__(256) void k_final(
    const float* __restrict__ rowfd, const float* __restrict__ rowrc,
    const float* __restrict__ t1p, float* __restrict__ out)
{
    const int t = threadIdx.x;
    double cr = 0.0, sf = 0.0, sr = 0.0;
    for (int i = t; i < NN * PPAD; i += 256) {
        double a = rowfd[i], b = rowrc[i];
        cr += a * b; sf += a; sr += b;
    }
    __shared__ double sh[256];
    sh[t] = cr; __syncthreads();
    for (int s = 128; s > 0; s >>= 1) { if (t < s) sh[t] += sh[t + s]; __syncthreads(); }
    cr = sh[0]; __syncthreads();
    sh[t] = sf; __syncthreads();
    for (int s = 128; s > 0; s >>= 1) { if (t < s) sh[t] += sh[t + s]; __syncthreads(); }
    sf = sh[0]; __syncthreads();
    sh[t] = sr; __syncthreads();
    for (int s = 128; s > 0; s >>= 1) { if (t < s) sh[t] += sh[t + s]; __syncthreads(); }
    sr = sh[0];
    if (t == 0) {
        double M = (double)NN * (double)PP * (double)PP;
        double t1 = (double)t1p[0];
        double bracket = t1 - cr / (double)PP + (sf / M) * sr;
        out[0] = (float)(-bracket / M);
    }
}

// ---------------------------------------------------------------------------
extern "C" void kernel_launch(void* const* d_in, const int* in_sizes, int n_in,
                              void* d_out, int out_size, void* d_ws, size_t ws_size,
                              hipStream_t stream)
{
    const float* orig_feats     = (const float*)d_in[0];
    const float* orig_feats_pos = (const float*)d_in[1];
    const float* orig_code      = (const float*)d_in[2];
    const float* orig_code_pos  = (const float*)d_in[3];
    const float* coords1        = (const float*)d_in[4];
    const float* coords2        = (const float*)d_in[5];

    // ---- workspace layout (total 89,669,888 B) ----
    char* ws = (char*)d_ws;
    float* t1    = (float*)(ws + 0);                      //      256 B
    float* rowfd = (float*)(ws + 256);                    //  106,496 B (NN*PPAD)
    float* rowrc = (float*)(ws + 106752);                 //  106,496 B
    float* nrmF  = (float*)(ws + 213248);                 //  212,992 B (2*NPTP)
    float* nrmC  = (float*)(ws + 426240);                 //  212,992 B
    const size_t zeroBytes = 639232;                      // t1+rowsums+nrms
    float* sclF  = (float*)(ws + 639232);                 //  212,992 B
    float* sclC  = (float*)(ws + 852224);                 //  212,992 B
    short* OF0 = (short*)(ws + 1065216);                  // [16][24][1664][32] bf16
    short* OF1 = (short*)(ws + 1065216 + 40894464ull);
    short* OC0 = (short*)(ws + 1065216 + 2*40894464ull);  // [16][2][1664][32] bf16
    short* OC1 = (short*)(ws + 1065216 + 2*40894464ull + 3407872ull);

    (void)hipMemsetAsync(d_ws, 0, zeroBytes, stream);   // t1/rowsums/nrms

    k_sample<<<dim3(3328), 256, 0, stream>>>(
        orig_feats, orig_feats_pos, orig_code, orig_code_pos,
        coords1, coords2, nrmF, nrmC, OF0, OF1, OC0, OC1);

    k_nrm<<<dim3((2*NPTP + 255)/256, 2), 256, 0, stream>>>(
        nrmF, nrmC, sclF, sclC);

    k_corr<<<dim3(1456), 512, 0, stream>>>(
        OF0, OF1, OC0, OC1, sclF, sclC, rowfd, rowrc, t1);

    k_final<<<1, 256, 0, stream>>>(rowfd, rowrc, t1, (float*)d_out);
}

// Round 4
// 262.553 us; speedup vs baseline: 1.6265x; 1.3050x over previous
//
#include <hip/hip_runtime.h>
#include <hip/hip_bf16.h>

// Problem constants
#define NN 16
#define CF 768
#define CC 64
#define HH 56
#define WW 56
#define SS 40
#define PP (SS*SS)          // 1600 positions per image
#define PPAD 1664           // padded to 13*128 for 128-tile GEMM
#define NPT (NN*PP)         // 25600
#define NPTP (NN*PPAD)      // 26624
#define HWP (HH*WW)         // 3136

typedef __attribute__((ext_vector_type(8))) short short8;
typedef __attribute__((ext_vector_type(4))) float f32x4;

typedef const __attribute__((address_space(1))) void* gas_p;
typedef __attribute__((address_space(3))) void* las_p;

__device__ __forceinline__ unsigned f2b(float f) {
    __hip_bfloat16 b = __float2bfloat16(f);
    return (unsigned)*(unsigned short*)&b;
}
__device__ __forceinline__ float bup(unsigned u, int hi) {
    unsigned bits = hi ? (u & 0xffff0000u) : (u << 16);
    return __uint_as_float(bits);
}

// Shared bilinear helper — EXACT same arithmetic as validated round-1 kernel.
__device__ __forceinline__ void bilin(float gx, float gy,
    int& o00, int& o01, int& o10, int& o11,
    float& w00, float& w01, float& w10, float& w11)
{
    float x = (gx + 1.f) * 0.5f * (float)(WW - 1);
    float y = (gy + 1.f) * 0.5f * (float)(HH - 1);
    x = fminf(fmaxf(x, 0.f), (float)(WW - 1));
    y = fminf(fmaxf(y, 0.f), (float)(HH - 1));
    float xf = floorf(x), yf = floorf(y);
    int x0 = (int)xf, y0 = (int)yf;
    int x1 = min(x0 + 1, WW - 1), y1 = min(y0 + 1, HH - 1);
    float wx = x - xf, wy = y - yf;
    w00 = (1.f-wx)*(1.f-wy); w01 = wx*(1.f-wy); w10 = (1.f-wx)*wy; w11 = wx*wy;
    o00 = y0*WW + x0; o01 = y0*WW + x1; o10 = y1*WW + x0; o11 = y1*WW + x1;
}

// ---------------------------------------------------------------------------
// Kernel 1: sampling — round 19: same block mapping / outputs / math as the
// validated round-15 kernel, but restructured as an 8-step per-channel
// pipeline: 2 x 16KB double-buffered LDS plane filled by global_load_lds
// (async, counted vmcnt(4) — next channel's 4 loads stay in flight), bilinear
// meta computed ONCE into registers. LDS 50KB -> 32KB (4-5 blocks/CU) and
// load(c+1) overlaps compute(c): removes the load<->compute convoy.
// ---------------------------------------------------------------------------
__global__ __launch_bounds__(256) void k_sample(
    const float* __restrict__ f0, const float* __restrict__ f1,
    const float* __restrict__ c0in, const float* __restrict__ c1in,
    const float* __restrict__ g0, const float* __restrict__ g1,
    float* __restrict__ nrmF, float* __restrict__ nrmC,
    short* __restrict__ OF0, short* __restrict__ OF1,
    short* __restrict__ OC0, short* __restrict__ OC1)
{
    // decode quarter-interleaved flat index (identical to validated kernel)
    const int flat = blockIdx.x;                       // [0, 3328)
    const int q    = (flat >> 3) & 3;                  // quarter
    const int u    = ((flat >> 5) << 3) | (flat & 7);  // [0, 832)
    const int set  = u / 416;                          // 26*16 = 416
    const int rem  = u % 416;
    const int n    = rem / 26;
    const int v    = rem % 26;                         // 0..23 feats, 24..25 code
    const bool isF = v < 24;
    const int ks   = isF ? v : v - 24;
    const int g    = ks * 4 + q;                       // 8-channel group index

    const float* src0; float* nrm; short* out; int NKS;
    if (isF) {
        src0 = (set ? f1 : f0) + ((size_t)n * CF + g * 8) * HWP;
        nrm  = nrmF + (size_t)set * NPTP;
        out  = set ? OF1 : OF0;
        NKS  = 24;
    } else {
        src0 = (set ? c1in : c0in) + ((size_t)n * CC + g * 8) * HWP;
        nrm  = nrmC + (size_t)set * NPTP;
        out  = set ? OC1 : OC0;
        NKS  = 2;
    }
    const float* gr = set ? g1 : g0;
    const int t = threadIdx.x;

    __shared__ float plane[2][4096];   // 2 x 16 KB double buffer (784 f4 used)

    // ---- per-position bilinear meta, computed once (was: twice) ----
    int   po[7], pdx[7], pdw[7];
    float pw[7][4];
    #pragma unroll
    for (int i = 0; i < 7; i++) {
        int p = t + i * 256;
        if (p < PP) {
            float2 gg = *(const float2*)&gr[2 * (n * PP + p)];
            int o00, o01, o10, o11; float w00, w01, w10, w11;
            bilin(gg.x*2.f - 1.f, gg.y*2.f - 1.f, o00, o01, o10, o11, w00, w01, w10, w11);
            po[i] = o00; pdx[i] = o01 - o00; pdw[i] = o10 - o00;
            pw[i][0] = w00; pw[i][1] = w01; pw[i][2] = w10; pw[i][3] = w11;
        } else {
            po[i] = 0; pdx[i] = 0; pdw[i] = 0;
            pw[i][0] = pw[i][1] = pw[i][2] = pw[i][3] = 0.f;   // pad -> exact 0
        }
    }

    auto* pl3 = (__attribute__((address_space(3))) char*)&plane[0][0];

    // stage channel C into buffer C&1: 4 x 16B per thread, LDS dest linear in
    // lane (uniform + lane*16); global src clamped to last line for the tail
    // (dup loads hit one 64B line -> ~no extra HBM).
#define ISSUE(C)                                                                    \
    do {                                                                            \
        const char* sp_ = (const char*)(src0 + (C) * HWP);                          \
        _Pragma("unroll")                                                           \
        for (int i_ = 0; i_ < 4; i_++) {                                            \
            int j_  = t + i_ * 256;                                                 \
            int jc_ = min(j_, 783);                                                 \
            __builtin_amdgcn_global_load_lds((gas_p)(sp_ + jc_ * 16),               \
                (las_p)(pl3 + (((C) & 1) * 16384 + j_ * 16)), 16, 0, 0);            \
        }                                                                           \
    } while (0)

    float ss[7];
    short ov[7][8] __attribute__((aligned(16)));
    #pragma unroll
    for (int i = 0; i < 7; i++) ss[i] = 0.f;

    ISSUE(0);
    #pragma unroll
    for (int c = 0; c < 8; c++) {
        if (c < 7) {
            ISSUE(c + 1);
            asm volatile("s_waitcnt vmcnt(4)" ::: "memory");   // my ch-c loads done
        } else {
            asm volatile("s_waitcnt vmcnt(0)" ::: "memory");
        }
        __builtin_amdgcn_sched_barrier(0);
        __builtin_amdgcn_s_barrier();              // all waves' ch-c loads done
        const float* pl = &plane[c & 1][0];
        #pragma unroll
        for (int i = 0; i < 7; i++) {
            float val = pw[i][0] * pl[po[i]]
                      + pw[i][1] * pl[po[i] + pdx[i]]
                      + pw[i][2] * pl[po[i] + pdw[i]]
                      + pw[i][3] * pl[po[i] + pdw[i] + pdx[i]];
            ss[i] += val * val;
            __hip_bfloat16 b = __float2bfloat16(val);
            ov[i][c] = *(short*)&b;
        }
        __builtin_amdgcn_sched_barrier(0);
        __builtin_amdgcn_s_barrier();              // compute done before reuse
    }
#undef ISSUE

    // [n][ks][p][32] layout: base of this block's quarter (identical)
    const size_t obase = ((size_t)(n * NKS + ks)) * PPAD * 32 + q * 8;
    #pragma unroll
    for (int i = 0; i < 7; i++) {
        int p = t + i * 256;
        if (p < PPAD) {
            *(short8*)&out[obase + (size_t)p * 32] = *(const short8*)&ov[i][0];
            if (p < PP) atomicAdd(&nrm[n * PPAD + p], ss[i]);
        }
    }
}

// ---------------------------------------------------------------------------
// Kernel 2: nrm -> scale (validated round 10). Pad rows -> scale 0.
// ---------------------------------------------------------------------------
__global__ __launch_bounds__(256) void k_nrm(
    const float* __restrict__ nrmF, const float* __restrict__ nrmC,
    float* __restrict__ sclF, float* __restrict__ sclC)
{
    const int i = blockIdx.x * 256 + threadIdx.x;    // [0, 2*NPTP)
    if (i >= 2 * NPTP) return;
    const float* nrm = blockIdx.y ? nrmC : nrmF;
    float*       scl = blockIdx.y ? sclC : sclF;
    const int p = i % PPAD;
    float s = (p < PP) ? 1.f / fmaxf(sqrtf(nrm[i]), 1e-10f) : 0.f;
    scl[i] = s;
}

// ---------------------------------------------------------------------------
// Kernel 3: fused dual correlation GEMM — VERBATIM round-15 kernel (proven
// 164us): 3-buffer counted-vmcnt pipeline, deferred epilogue, XOR swizzle,
// XCD swizzle, [n][ks][p][32] layout -> 1KB-contiguous staging.
// ---------------------------------------------------------------------------
__global__ __launch_bounds__(256, 3) void k_corr(
    const short* __restrict__ A, const short* __restrict__ B,
    const short* __restrict__ C, const short* __restrict__ D,
    const float* __restrict__ sF, const float* __restrict__ sC,
    float* __restrict__ rowfd, float* __restrict__ rowrc, float* __restrict__ t1out)
{
    // XCD-chunked swizzle: 2704 blocks = 8 XCDs x 338; x fastest within chunk
    const int flat = blockIdx.x;
    const int v   = (flat & 7) * 338 + (flat >> 3);
    const int n   = v / 169;
    const int rr  = v - n * 169;
    const int bp1 = (rr / 13) * 128;
    const int bp2 = (rr % 13) * 128;

    __shared__ short As[3][4096];   // 3 buffers x 8 KB
    __shared__ short Bs[3][4096];

    const int t    = threadIdx.x;
    const int wv   = t >> 6, lane = t & 63;
    const int wm   = wv >> 1, wn = wv & 1;
    const int frow = lane & 15, fcg = lane >> 4;     // fragment row / k-chunk
    const int fslot = fcg ^ ((frow >> 1) & 3);       // bank-swizzled slot

    // staging geometry: chunk g = (wv*2+i)*64 + lane, g in [0,512)
    const int sg0  = wv * 2 * 64 + lane;
    const int row0 = sg0 >> 2,        cg0 = (sg0 & 3) ^ ((row0 >> 1) & 3);
    const int sg1  = sg0 + 64;
    const int row1 = sg1 >> 2,        cg1 = (sg1 & 3) ^ ((row1 >> 1) & 3);

    const size_t kstep = (size_t)PPAD * 32;          // shorts per BK=32 step
    const short* fdA = A + (size_t)n * 24 * kstep;
    const short* fdB = B + (size_t)n * 24 * kstep;
    const short* cdC = C + (size_t)n * 2 * kstep;
    const short* cdD = D + (size_t)n * 2 * kstep;
    const size_t toA0 = (size_t)(bp1 + row0) * 32 + cg0 * 8;
    const size_t toA1 = (size_t)(bp1 + row1) * 32 + cg1 * 8;
    const size_t toB0 = (size_t)(bp2 + row0) * 32 + cg0 * 8;
    const size_t toB1 = (size_t)(bp2 + row1) * 32 + cg1 * 8;

    auto* As3 = (__attribute__((address_space(3))) short*)&As[0][0];
    auto* Bs3 = (__attribute__((address_space(3))) short*)&Bs[0][0];
    const int ldsA0 = (wv * 2    ) * 512;  // shorts within one buffer
    const int ldsA1 = (wv * 2 + 1) * 512;

#define STAGE(PA, PB, OFF, BUF)                                                     \
    do {                                                                            \
        const size_t off_ = (OFF);                                                  \
        const int b_ = (BUF) * 4096;                                                \
        __builtin_amdgcn_global_load_lds((gas_p)((PA) + toA0 + off_),               \
                                         (las_p)(As3 + b_ + ldsA0), 16, 0, 0);      \
        __builtin_amdgcn_global_load_lds((gas_p)((PA) + toA1 + off_),               \
                                         (las_p)(As3 + b_ + ldsA1), 16, 0, 0);      \
        __builtin_amdgcn_global_load_lds((gas_p)((PB) + toB0 + off_),               \
                                         (las_p)(Bs3 + b_ + ldsA0), 16, 0, 0);      \
        __builtin_amdgcn_global_load_lds((gas_p)((PB) + toB1 + off_),               \
                                         (las_p)(Bs3 + b_ + ldsA1), 16, 0, 0);      \
    } while (0)

#define COMPUTE(BUF, ACC)                                                           \
    do {                                                                            \
        short8 af[4], bf[4];                                                        \
        _Pragma("unroll")                                                           \
        for (int m = 0; m < 4; m++)                                                 \
            af[m] = *(const short8*)&As[BUF][(wm*64 + m*16 + frow)*32 + fslot*8];   \
        _Pragma("unroll")                                                           \
        for (int q = 0; q < 4; q++)                                                 \
            bf[q] = *(const short8*)&Bs[BUF][(wn*64 + q*16 + frow)*32 + fslot*8];   \
        _Pragma("unroll")                                                           \
        for (int m = 0; m < 4; m++)                                                 \
            _Pragma("unroll")                                                       \
            for (int q = 0; q < 4; q++)                                             \
                ACC[m][q] = __builtin_amdgcn_mfma_f32_16x16x32_bf16(af[m], bf[q], ACC[m][q], 0, 0, 0); \
    } while (0)

#define WAITV4  do { asm volatile("s_waitcnt vmcnt(4)" ::: "memory");               \
                     __builtin_amdgcn_sched_barrier(0);                             \
                     __builtin_amdgcn_s_barrier(); } while (0)
#define WAITV0  do { asm volatile("s_waitcnt vmcnt(0)" ::: "memory");               \
                     __builtin_amdgcn_sched_barrier(0);                             \
                     __builtin_amdgcn_s_barrier(); } while (0)

    unsigned pcd[4][4][2];   // raw relu(cd) packed as bf16 pairs (32 VGPR)

    // ---- prologue: stage cd steps 0,1 ----
    STAGE(cdC, cdD, 0, 0);
    STAGE(cdC, cdD, kstep, 1);

    // ---- cd steps (t=0,1) ----
    {
        f32x4 acccd[4][4];
        #pragma unroll
        for (int m = 0; m < 4; m++)
            #pragma unroll
            for (int q = 0; q < 4; q++)
                #pragma unroll
                for (int r = 0; r < 4; r++) acccd[m][q][r] = 0.f;

        WAITV4;                        // t=0: cd0 landed
        STAGE(fdA, fdB, 0, 2);         // stage fd step 0 -> buf2
        COMPUTE(0, acccd);
        WAITV4;                        // t=1: cd1 landed
        STAGE(fdA, fdB, 1 * kstep, 0); // stage fd step 1 -> buf0
        COMPUTE(1, acccd);

        // pack raw relu(cd) -> bf16 pairs (pure VALU; scales deferred)
        #pragma unroll
        for (int m = 0; m < 4; m++)
            #pragma unroll
            for (int q = 0; q < 4; q++) {
                float r0 = fmaxf(acccd[m][q][0], 0.f);
                float r1 = fmaxf(acccd[m][q][1], 0.f);
                float r2 = fmaxf(acccd[m][q][2], 0.f);
                float r3 = fmaxf(acccd[m][q][3], 0.f);
                pcd[m][q][0] = f2b(r0) | (f2b(r1) << 16);
                pcd[m][q][1] = f2b(r2) | (f2b(r3) << 16);
            }
    }   // acccd dies (AGPRs freed before accfd)

    // ---- fd steps (pipeline slots; fd K-steps 0..23) ----
    f32x4 accfd[4][4];
    #pragma unroll
    for (int m = 0; m < 4; m++)
        #pragma unroll
        for (int q = 0; q < 4; q++)
            #pragma unroll
            for (int r = 0; r < 4; r++) accfd[m][q][r] = 0.f;

    for (int kp = 0; kp < 8; kp++) {
        const size_t tb = (size_t)(3 * kp) * kstep;
        // slot 0: fd step 3kp, compute buf2, stage fd step 3kp+2 -> buf1
        WAITV4;
        STAGE(fdA, fdB, tb + 2 * kstep, 1);
        COMPUTE(2, accfd);
        // slot 1: fd step 3kp+1, compute buf0, stage 3kp+3 -> buf2
        WAITV4;
        if (kp < 7) STAGE(fdA, fdB, tb + 3 * kstep, 2);
        COMPUTE(0, accfd);
        // slot 2: fd step 3kp+2, compute buf1, stage 3kp+4 -> buf0
        if (kp < 7) {
            WAITV4;
            STAGE(fdA, fdB, tb + 4 * kstep, 0);
        } else {
            WAITV0;
        }
        COMPUTE(1, accfd);
    }
#undef STAGE
#undef COMPUTE
#undef WAITV4
#undef WAITV0

    // ---- single deferred epilogue: scales + t1 + rowfd + rowrc ----
    // C/D layout: col = lane&15, row = (lane>>4)*4 + reg
    float scc_[4], sfc_[4];
    #pragma unroll
    for (int q = 0; q < 4; q++) {
        size_t colp = (size_t)NPTP + (size_t)n * PPAD + bp2 + wn*64 + q*16 + frow;
        scc_[q] = sC[colp];
        sfc_[q] = sF[colp];
    }

    float t1 = 0.f;
    #pragma unroll
    for (int m = 0; m < 4; m++) {
        #pragma unroll
        for (int r = 0; r < 4; r++) {
            size_t rowp = (size_t)n * PPAD + bp1 + wm*64 + m*16 + fcg*4 + r;
            float scr = sC[rowp];
            float sfr = sF[rowp];
            float sf = 0.f, sr = 0.f;
            #pragma unroll
            for (int q = 0; q < 4; q++) {
                float fdv = accfd[m][q][r] * sfr * sfc_[q];
                float rcv = bup(pcd[m][q][r >> 1], r & 1) * scr * scc_[q];
                t1 += rcv * fdv;
                sf += fdv;
                sr += rcv;
            }
            #pragma unroll
            for (int d = 1; d < 16; d <<= 1) {
                sf += __shfl_xor(sf, d, 64);
                sr += __shfl_xor(sr, d, 64);
            }
            if ((lane & 15) == 0) {
                int row = bp1 + wm*64 + m*16 + fcg*4 + r;
                atomicAdd(&rowfd[n * PPAD + row], sf);
                atomicAdd(&rowrc[n * PPAD + row], sr);
            }
        }
    }
    #pragma unroll
    for (int d = 1; d < 64; d <<= 1) t1 += __shfl_xor(t1, d, 64);
    __shared__ float t1s[4];
    if (lane == 0) t1s[wv] = t1;
    __syncthreads();
    if (t == 0) atomicAdd(t1out, t1s[0] + t1s[1] + t1s[2] + t1s[3]);
}

// ---------------------------------------------------------------------------
// Kernel 4: finalize. loss = -(T1 - cross/PP + (Sfd/M)*Src)/M
// Round 19: 1024 threads (26 grid-stride iters instead of 104) for MLP.
// ---------------------------------------------------------------------------
__global__ __launch_bounds__(1024) void k_final(
    const float* __restrict__ rowfd, const float* __restrict__ rowrc,
    const float* __restrict__ t1p, float* __restrict__ out)
{
    const int t = threadIdx.x;
    double cr = 0.0, sf = 0.0, sr = 0.0;
    for (int i = t; i < NN * PPAD; i += 1024) {
        double a = rowfd[i], b = rowrc[i];
        cr += a * b; sf += a; sr += b;
    }
    __shared__ double sh[1024];
    sh[t] = cr; __syncthreads();
    for (int s = 512; s > 0; s >>= 1) { if (t < s) sh[t] += sh[t + s]; __syncthreads(); }
    cr = sh[0]; __syncthreads();
    sh[t] = sf; __syncthreads();
    for (int s = 512; s > 0; s >>= 1) { if (t < s) sh[t] += sh[t + s]; __syncthreads(); }
    sf = sh[0]; __syncthreads();
    sh[t] = sr; __syncthreads();
    for (int s = 512; s > 0; s >>= 1) { if (t < s) sh[t] += sh[t + s]; __syncthreads(); }
    sr = sh[0];
    if (t == 0) {
        double M = (double)NN * (double)PP * (double)PP;
        double t1 = (double)t1p[0];
        double bracket = t1 - cr / (double)PP + (sf / M) * sr;
        out[0] = (float)(-bracket / M);
    }
}

// ---------------------------------------------------------------------------
extern "C" void kernel_launch(void* const* d_in, const int* in_sizes, int n_in,
                              void* d_out, int out_size, void* d_ws, size_t ws_size,
                              hipStream_t stream)
{
    const float* orig_feats     = (const float*)d_in[0];
    const float* orig_feats_pos = (const float*)d_in[1];
    const float* orig_code      = (const float*)d_in[2];
    const float* orig_code_pos  = (const float*)d_in[3];
    const float* coords1        = (const float*)d_in[4];
    const float* coords2        = (const float*)d_in[5];

    // ---- workspace layout (total 89,669,888 B) ----
    char* ws = (char*)d_ws;
    float* t1    = (float*)(ws + 0);                      //      256 B
    float* rowfd = (float*)(ws + 256);                    //  106,496 B (NN*PPAD)
    float* rowrc = (float*)(ws + 106752);                 //  106,496 B
    float* nrmF  = (float*)(ws + 213248);                 //  212,992 B (2*NPTP)
    float* nrmC  = (float*)(ws + 426240);                 //  212,992 B
    const size_t zeroBytes = 639232;                      // t1+rowsums+nrms
    float* sclF  = (float*)(ws + 639232);                 //  212,992 B
    float* sclC  = (float*)(ws + 852224);                 //  212,992 B
    short* OF0 = (short*)(ws + 1065216);                  // [16][24][1664][32] bf16
    short* OF1 = (short*)(ws + 1065216 + 40894464ull);
    short* OC0 = (short*)(ws + 1065216 + 2*40894464ull);  // [16][2][1664][32] bf16
    short* OC1 = (short*)(ws + 1065216 + 2*40894464ull + 3407872ull);

    (void)hipMemsetAsync(d_ws, 0, zeroBytes, stream);   // t1/rowsums/nrms

    k_sample<<<dim3(3328), 256, 0, stream>>>(
        orig_feats, orig_feats_pos, orig_code, orig_code_pos,
        coords1, coords2, nrmF, nrmC, OF0, OF1, OC0, OC1);

    k_nrm<<<dim3((2*NPTP + 255)/256, 2), 256, 0, stream>>>(
        nrmF, nrmC, sclF, sclC);

    k_corr<<<dim3(2704), 256, 0, stream>>>(
        OF0, OF1, OC0, OC1, sclF, sclC, rowfd, rowrc, t1);

    k_final<<<1, 1024, 0, stream>>>(rowfd, rowrc, t1, (float*)d_out);
}